// Round 3
// baseline (34.284 us; speedup 1.0000x reference)
//
#include <hip/hip_runtime.h>
#include <hip/hip_bf16.h>
#include <math.h>

#define NT 256
#define VSTRIDE 552          // 20 zero-pad | 512 cols | 20 zero-pad  (stride*4B is 16B-aligned)

// Sliding-35 max via register doubling over w[50] -> 16 outputs: out[k]=max(w32[k],w32[k+3])
#define DOUBLE50(w)                                                              \
    _Pragma("unroll") for (int i = 0; i <= 48; ++i) w[i] = fmaxf(w[i], w[i+1]);  \
    _Pragma("unroll") for (int i = 0; i <= 46; ++i) w[i] = fmaxf(w[i], w[i+2]);  \
    _Pragma("unroll") for (int i = 0; i <= 42; ++i) w[i] = fmaxf(w[i], w[i+4]);  \
    _Pragma("unroll") for (int i = 0; i <= 34; ++i) w[i] = fmaxf(w[i], w[i+8]);  \
    _Pragma("unroll") for (int i = 0; i <= 18; ++i) w[i] = fmaxf(w[i], w[i+16]);

// ---- K1: vertical sliding-35 max of y = 1 - min_c(x), direct from global ----
// 1024 blocks: (batch b, 16-row chunk t, col half). Thread owns 1 col x 16 out rows.
template<typename VT>
__global__ __launch_bounds__(NT)
void dark_vpass(const float* __restrict__ x, VT* __restrict__ V) {
    const int tid = threadIdx.x;
    const int bid = blockIdx.x;
    const int swz = (bid & 7) * 128 + (bid >> 3);   // XCD k -> batches 2k,2k+1
    const int b    = swz >> 6;
    const int rest = swz & 63;
    const int t    = rest >> 1;                      // out rows 16t..16t+15
    const int col  = (rest & 1) * 256 + tid;         // 0..511, lanes consecutive -> coalesced
    const float* xb = x + (size_t)b * 786432u;
    VT* vb = V + (size_t)b * (512 * VSTRIDE);

    float w[50];
    #pragma unroll
    for (int k = 0; k < 50; ++k) {
        const int gh = 16 * t - 17 + k;
        float y = 0.0f;                              // pad value (y>=0 always, so 0 is neutral)
        if ((unsigned)gh < 512u) {                   // uniform branch per k
            const float* p = xb + gh * 512 + col;
            y = 1.0f - fminf(p[0], fminf(p[262144], p[524288]));
        }
        w[k] = y;
    }
    DOUBLE50(w)
    #pragma unroll
    for (int kk = 0; kk < 16; ++kk)
        vb[(16 * t + kk) * VSTRIDE + 20 + col] = (VT)fmaxf(w[kk], w[kk + 3]);
    if (col < 20) {                                  // zero left pad
        #pragma unroll
        for (int kk = 0; kk < 16; ++kk) vb[(16 * t + kk) * VSTRIDE + col] = (VT)0.0f;
    }
    if (col >= 492) {                                // zero right pad (532..551)
        #pragma unroll
        for (int kk = 0; kk < 16; ++kk) vb[(16 * t + kk) * VSTRIDE + col + 40] = (VT)0.0f;
    }
}

// ---- K2: horizontal sliding-35 max + partial sum. Thread owns 1 row x 16 out cols ----
// Buffer col index 16c+i maps to image col 16c-20+i; window for out kk is buffer [3+kk, 37+kk].
template<typename VT>
__global__ __launch_bounds__(NT)
void dark_hpass(const VT* __restrict__ V, float* __restrict__ part) {
    const int tid = threadIdx.x;
    const int bid = blockIdx.x;
    const int swz = (bid & 7) * 128 + (bid >> 3);    // same mapping as K1 -> L2-local V reuse
    const int b   = swz >> 6;
    const int rg  = swz & 63;
    const int row = rg * 8 + (tid >> 5);
    const int c   = tid & 31;                        // 16-col output chunk
    const VT* vrow = V + (size_t)b * (512 * VSTRIDE) + row * VSTRIDE + 16 * c;

    float w[56];
    if constexpr (sizeof(VT) == 4) {
        #pragma unroll
        for (int i = 0; i < 14; ++i) {
            const float4 q = *(const float4*)((const float*)vrow + 4 * i);
            w[4*i] = q.x; w[4*i+1] = q.y; w[4*i+2] = q.z; w[4*i+3] = q.w;
        }
    } else {
        #pragma unroll
        for (int i = 0; i < 56; ++i) w[i] = (float)vrow[i];
    }
    #pragma unroll
    for (int i = 3; i <= 51; ++i) w[i] = fmaxf(w[i], w[i + 1]);
    #pragma unroll
    for (int i = 3; i <= 49; ++i) w[i] = fmaxf(w[i], w[i + 2]);
    #pragma unroll
    for (int i = 3; i <= 45; ++i) w[i] = fmaxf(w[i], w[i + 4]);
    #pragma unroll
    for (int i = 3; i <= 37; ++i) w[i] = fmaxf(w[i], w[i + 8]);
    #pragma unroll
    for (int i = 3; i <= 21; ++i) w[i] = fmaxf(w[i], w[i + 16]);
    float s = 0.0f;
    #pragma unroll
    for (int kk = 0; kk < 16; ++kk) s += fabsf(fmaxf(w[3 + kk], w[6 + kk]));

    #pragma unroll
    for (int off = 32; off; off >>= 1) s += __shfl_down(s, off);
    __shared__ float red[4];
    if ((tid & 63) == 0) red[tid >> 6] = s;
    __syncthreads();
    if (tid == 0) part[bid] = red[0] + red[1] + red[2] + red[3];
}

__global__ void dark_reduce(const float* __restrict__ part, float* __restrict__ out, int n) {
    float s = 0.0f;
    for (int i = threadIdx.x; i < n; i += NT) s += part[i];
    #pragma unroll
    for (int off = 32; off; off >>= 1) s += __shfl_down(s, off);
    __shared__ float w[NT / 64];
    if ((threadIdx.x & 63) == 0) w[threadIdx.x >> 6] = s;
    __syncthreads();
    if (threadIdx.x == 0) {
        float t = 0.0f;
        #pragma unroll
        for (int i = 0; i < NT / 64; ++i) t += w[i];
        out[0] = -t * (1.0f / 4194304.0f);   // -mean over 16*512*512
    }
}

extern "C" void kernel_launch(void* const* d_in, const int* in_sizes, int n_in,
                              void* d_out, int out_size, void* d_ws, size_t ws_size,
                              hipStream_t stream) {
    const float* x = (const float*)d_in[0];
    float* out  = (float*)d_out;
    float* part = (float*)d_ws;                       // 1024 floats
    void*  vbuf = (void*)((char*)d_ws + 4096);

    const size_t vElems = (size_t)16 * 512 * VSTRIDE;
    if (ws_size >= 4096 + vElems * sizeof(float)) {
        float* V = (float*)vbuf;
        hipLaunchKernelGGL((dark_vpass<float>), dim3(1024), dim3(NT), 0, stream, x, V);
        hipLaunchKernelGGL((dark_hpass<float>), dim3(1024), dim3(NT), 0, stream, V, part);
    } else {
        __hip_bfloat16* V = (__hip_bfloat16*)vbuf;    // fallback: 9.1 MB, err ~2e-3 << 2e-2
        hipLaunchKernelGGL((dark_vpass<__hip_bfloat16>), dim3(1024), dim3(NT), 0, stream, x, V);
        hipLaunchKernelGGL((dark_hpass<__hip_bfloat16>), dim3(1024), dim3(NT), 0, stream, V, part);
    }
    hipLaunchKernelGGL(dark_reduce, dim3(1), dim3(NT), 0, stream, part, out, 1024);
}